// Round 21
// baseline (360.274 us; speedup 1.0000x reference)
//
#include <hip/hip_runtime.h>
#include <hip/hip_bf16.h>

typedef __attribute__((ext_vector_type(8))) short s16x8;
typedef __attribute__((ext_vector_type(4))) short s16x4;
typedef __attribute__((ext_vector_type(4))) float f32x4;

#define B_ 2
#define L_ 2048
#define E_ 2048
#define H_ 16
#define D_ 128

__device__ __forceinline__ float b2f(short s) {
    unsigned u = ((unsigned)(unsigned short)s) << 16;
    return __builtin_bit_cast(float, u);
}
__device__ __forceinline__ short f2b(float f) {
    unsigned u = __builtin_bit_cast(unsigned, f);
    unsigned r = u + 0x7FFFu + ((u >> 16) & 1u);
    return (short)(r >> 16);
}

__device__ __forceinline__ void lds16(const short* g, short* l) {
    __builtin_amdgcn_global_load_lds(
        (const __attribute__((address_space(1))) void*)g,
        (__attribute__((address_space(3))) void*)l, 16, 0, 0);
}

// ---------------- prep: fp32->bf16 convert (3 tensors) + RoPE trig table ----------------
__global__ __launch_bounds__(256) void prep_kernel(const float* __restrict__ x,
                                                   const float* __restrict__ wq,
                                                   const float* __restrict__ wo,
                                                   short* __restrict__ xb,
                                                   short* __restrict__ wqb,
                                                   short* __restrict__ wob,
                                                   float2* __restrict__ tab) {
    const int blk = blockIdx.x;
    if (blk < 24576) {
        int i = blk * 256 + threadIdx.x;       // over 6291456 float4s
        const float* in; short* out; int idx;
        if (i < 2097152)        { in = x;  out = xb;  idx = i; }
        else if (i < 5242880)   { in = wq; out = wqb; idx = i - 2097152; }
        else                    { in = wo; out = wob; idx = i - 5242880; }
        float4 v = ((const float4*)in)[idx];
        s16x4 o;
        o.x = f2b(v.x); o.y = f2b(v.y); o.z = f2b(v.z); o.w = f2b(v.w);
        ((s16x4*)out)[idx] = o;
    } else {
        int i = (blk - 24576) * 256 + threadIdx.x;   // L * 64 = 131072
        int l = i >> 6, f = i & 63;
        float inv = expf(-(float)(2 * f) * (9.210340371976184f / 128.f));
        float ang = (float)l * inv;
        tab[i] = make_float2(cosf(ang), sinf(ang));
    }
}

// ---------------- GEMM1 fused: reg-staged A + LDS B (LDS-BW diet) ----------------
// LDS-BW model: old core moved 96 KB LDS per block per K-tile (A+B, wr+rd) ->
// 1500 cyc/CU at 4 blocks/CU vs 640 cyc MFMA demand = 43% MfmaUtil (measured
// 44%). A's swizzled-LDS read chain cancels to the contiguous global chunk
// A[row][kt+(ks*4+kg)*8], so load it straight global->VGPR (per-lane addr,
// L2-hot: A reused by 48 n-blocks). LDS now carries only B: 48 KB/K-tile.
__global__ __launch_bounds__(256, 2)
void gemm_qkv(const short* __restrict__ A, const short* __restrict__ Bm,
              const float* __restrict__ bias, const float2* __restrict__ trig,
              short* __restrict__ q, short* __restrict__ k, short* __restrict__ vt,
              int M, int N, int K) {
    __shared__ __align__(16) char smem[128 * 136 * 2];   // 34816 B
    short* Bs = (short*)smem;                 // 128*64 shorts (16 KB)
    short* Vt = (short*)smem;                 // [128 d][136 l] overlay
    const int t = threadIdx.x;
    const int wid = t >> 6, lane = t & 63;
    const int fr = lane & 15, kg = lane >> 4;
    const int m0 = blockIdx.x * 128, n0 = blockIdx.y * 128;
    const int wm = (wid >> 1) * 64, wn = (wid & 1) * 64;
    f32x4 acc[4][4] = {};

    {
        // B staging (unchanged): pre-swizzled source col, linear LDS dest
        const int srow8 = lane >> 3;
        const int scol = ((lane & 7) ^ srow8) * 8;
        const short* gb = Bm + (size_t)(n0 + wid * 32 + srow8) * K + scol;
        short* lB = Bs + wid * 2048;
        // A fragments: straight global loads (per-lane), own 64-row strip
        const short* pa = A + (size_t)(m0 + wm + fr) * K + kg * 8;

        for (int kt = 0; kt < K; kt += 64) {
#pragma unroll
            for (int c = 0; c < 4; c++)
                lds16(gb + kt + (size_t)(c * 8) * K, lB + c * 512);
            s16x8 af[2][4];
#pragma unroll
            for (int ks = 0; ks < 2; ks++)
#pragma unroll
                for (int i = 0; i < 4; i++)
                    af[ks][i] = *(const s16x8*)(pa + (size_t)(i * 16) * K + kt + ks * 32);
            __syncthreads();     // drains lds16 + af loads
#pragma unroll
            for (int ks = 0; ks < 2; ks++) {
                s16x8 bf[4];
#pragma unroll
                for (int i = 0; i < 4; i++)
                    bf[i] = *(const s16x8*)(Bs + (wn + i * 16 + fr) * 64 +
                                            (((ks * 4 + kg) ^ (fr & 7)) * 8));
#pragma unroll
                for (int mi = 0; mi < 4; mi++)
#pragma unroll
                    for (int ni = 0; ni < 4; ni++)
                        acc[mi][ni] = __builtin_amdgcn_mfma_f32_16x16x32_bf16(
                            af[ks][mi], bf[ni], acc[mi][ni], 0, 0, 0);
            }
            __syncthreads();
        }
    }

    const int part = blockIdx.y >> 4;         // 0=q 1=k 2=v
    const int h = blockIdx.y & 15;
    const int b = m0 >> 11;
    const int l0b = m0 & 2047;
    const size_t bh = (size_t)(b * 16 + h);

    if (part < 2) {
        short* dst = part ? k : q;
        const float qs = part ? 1.0f : 0.08838834764831845f;
#pragma unroll
        for (int mi = 0; mi < 4; mi++) {
#pragma unroll
            for (int ni = 0; ni < 4; ni++) {
                const int dcol = wn + ni * 16 + fr;
                const float bv = bias[n0 + dcol];
#pragma unroll
                for (int r = 0; r < 4; r++) {
                    const int l = l0b + wm + mi * 16 + kg * 4 + r;
                    float vv = (acc[mi][ni][r] + bv) * qs;
                    float other = __shfl_xor(vv, 1);
                    float x0 = (fr & 1) ? other : vv;
                    float x1 = (fr & 1) ? vv : other;
                    float2 cs = trig[l * 64 + (dcol >> 1)];
                    float outv = (fr & 1) ? (x1 * cs.x + x0 * cs.y)
                                          : (x0 * cs.x - x1 * cs.y);
                    dst[(bh * L_ + l) * D_ + dcol] = f2b(outv);
                }
            }
        }
    } else {
        // v: transpose through LDS, write (B,H,D,L) coalesced
#pragma unroll
        for (int mi = 0; mi < 4; mi++) {
#pragma unroll
            for (int ni = 0; ni < 4; ni++) {
                const int dcol = wn + ni * 16 + fr;
                const float bv = bias[n0 + dcol];
#pragma unroll
                for (int r = 0; r < 4; r++) {
                    const int lloc = wm + mi * 16 + kg * 4 + r;
                    Vt[dcol * 136 + lloc] = f2b(acc[mi][ni][r] + bv);
                }
            }
        }
        __syncthreads();
        const int d = t >> 1, lh2 = (t & 1) * 64;
#pragma unroll
        for (int ps = 0; ps < 8; ps++) {
            const int ll = lh2 + ps * 8;
            s16x8 v8 = *(const s16x8*)(Vt + d * 136 + ll);
            *(s16x8*)(vt + (bh * D_ + d) * L_ + l0b + ll) = v8;
        }
    }
}

// ======== shared BK=64 GEMM core (128x128 tile, 4 waves, T2 swizzle) ========
#define GEMM_CORE_BK64(A_, B_ptr, K_)                                          \
    const int srow8 = lane >> 3;                                               \
    const int scol = ((lane & 7) ^ srow8) * 8;                                 \
    const short* ga = A_ + (size_t)(m0 + wid * 32 + srow8) * K_ + scol;        \
    const short* gb = B_ptr + (size_t)(n0 + wid * 32 + srow8) * K_ + scol;     \
    short* lA = As + wid * 2048;                                               \
    short* lB = Bs + wid * 2048;                                               \
    for (int kt = 0; kt < K_; kt += 64) {                                      \
        _Pragma("unroll")                                                      \
        for (int c = 0; c < 4; c++) {                                          \
            lds16(ga + kt + (size_t)(c * 8) * K_, lA + c * 512);               \
            lds16(gb + kt + (size_t)(c * 8) * K_, lB + c * 512);               \
        }                                                                      \
        __syncthreads();                                                       \
        _Pragma("unroll")                                                      \
        for (int ks = 0; ks < 2; ks++) {                                       \
            s16x8 af[4], bf[4];                                                \
            _Pragma("unroll")                                                  \
            for (int i = 0; i < 4; i++) {                                      \
                af[i] = *(const s16x8*)(As + (wm + i * 16 + fr) * 64 +         \
                                        (((ks * 4 + kg) ^ (fr & 7)) * 8));     \
                bf[i] = *(const s16x8*)(Bs + (wn + i * 16 + fr) * 64 +         \
                                        (((ks * 4 + kg) ^ (fr & 7)) * 8));     \
            }                                                                  \
            _Pragma("unroll")                                                  \
            for (int mi = 0; mi < 4; mi++)                                     \
                _Pragma("unroll")                                              \
                for (int ni = 0; ni < 4; ni++)                                 \
                    acc[mi][ni] = __builtin_amdgcn_mfma_f32_16x16x32_bf16(     \
                        af[mi], bf[ni], acc[mi][ni], 0, 0, 0);                 \
        }                                                                      \
        __syncthreads();                                                       \
    }

// ---------------- GEMM2 C[M,N] = A[M,K] * B[N,K]^T + bias (BK=64) ----------------
__global__ __launch_bounds__(256, 2)
void gemm_bt(const short* __restrict__ A, const short* __restrict__ Bm,
             const float* __restrict__ bias, float* __restrict__ C,
             int M, int N, int K) {
    __shared__ __align__(16) short As[128 * 64];
    __shared__ __align__(16) short Bs[128 * 64];
    const int t = threadIdx.x;
    const int wid = t >> 6, lane = t & 63;
    const int fr = lane & 15, kg = lane >> 4;
    const int m0 = blockIdx.x * 128, n0 = blockIdx.y * 128;
    const int wm = (wid >> 1) * 64, wn = (wid & 1) * 64;
    f32x4 acc[4][4] = {};

    GEMM_CORE_BK64(A, Bm, K)

#pragma unroll
    for (int mi = 0; mi < 4; mi++) {
#pragma unroll
        for (int ni = 0; ni < 4; ni++) {
            int gn = n0 + wn + ni * 16 + fr;
            float bv = bias[gn];
#pragma unroll
            for (int r = 0; r < 4; r++) {
                int gm = m0 + wm + mi * 16 + kg * 4 + r;
                C[(size_t)gm * N + gn] = acc[mi][ni][r] + bv;
            }
        }
    }
}

// ---------------- causal flash attention: uniform-work q-tile pairs + T14 reg-staging ----------------
// (r10 structure; O epilogue coalesced through the per-wave Ps slot)
__global__ __launch_bounds__(256, 2)
void attn_kernel(const short* __restrict__ Q, const short* __restrict__ Kb,
                 const short* __restrict__ Vt, short* __restrict__ O) {
    __shared__ __align__(16) short Ks[64 * 128];   // [s][d] swizzled
    __shared__ __align__(16) short Vs[128 * 64];   // [d][s] swizzled
    __shared__ __align__(16) short Ps[4 * 16 * 64];
    const int t = threadIdx.x;
    const int wid = t >> 6, lane = t & 63;
    const int fr = lane & 15, kg = lane >> 4;
    const int bid = blockIdx.x;
    const int qp = bid & 15, bh = bid >> 4;   // 512 blocks: 16 pairs x 32 bh
    const int b = bh >> 4, h = bh & 15;
    const size_t base = (size_t)bh * (L_ * D_);

    const int rr = t >> 4, c16 = t & 15;      // K staging map
    const int dr = t >> 3, lg2 = t & 7;       // V staging map

    s16x8 kreg[4], vreg[4];
#define LOADKV(s0v) { _Pragma("unroll")                                        \
    for (int it = 0; it < 4; it++) {                                           \
        kreg[it] = *(const s16x8*)(Kb + base + (size_t)((s0v) + it * 16 + rr) * D_ + c16 * 8); \
        vreg[it] = *(const s16x8*)(Vt + base + (size_t)(it * 32 + dr) * L_ + (s0v) + lg2 * 8); \
    } }
#define WRITEKV() { _Pragma("unroll")                                          \
    for (int it = 0; it < 4; it++) {                                           \
        int row = it * 16 + rr;                                                \
        *(s16x8*)((char*)Ks + row * 256 + ((c16 * 16) ^ ((row & 7) << 4))) = kreg[it]; \
        int d = it * 32 + dr;                                                  \
        *(s16x8*)((char*)Vs + d * 128 + ((lg2 * 16) ^ ((d & 7) << 4))) = vreg[it]; \
    } }

    LOADKV(0);
    WRITEKV();
    __syncthreads();

    for (int ph = 0; ph < 2; ph++) {
        const int qt = ph ? (31 - qp) : qp;
        const int q0 = qt << 6;
        s16x8 qa[4];
        {
            const short* qptr = Q + base + (size_t)(q0 + wid * 16 + fr) * D_ + kg * 8;
#pragma unroll
            for (int ch = 0; ch < 4; ch++) qa[ch] = *(const s16x8*)(qptr + ch * 32);
        }
        f32x4 oacc[8] = {};
        float mrow[4], lrow[4];
#pragma unroll
        for (int r = 0; r < 4; r++) { mrow[r] = -1e30f; lrow[r] = 0.f; }

        const int ntile = qt + 1;
        for (int ti = 0; ti < ntile; ti++) {
            const int s0 = ti << 6;
            const int nxt = (ti + 1 < ntile) ? (s0 + 64) : (ph == 0 ? 0 : -1);
            if (nxt >= 0) LOADKV(nxt);
            f32x4 sacc[4] = {};
            __builtin_amdgcn_s_setprio(1);
#pragma unroll
            for (int ch = 0; ch < 4; ch++) {
#pragma unroll
                for (int ni = 0; ni < 4; ni++) {
                    int row = ni * 16 + fr;
                    s16x8 kf = *(const s16x8*)((char*)Ks + row * 256 +
                                               ((ch * 64 + kg * 16) ^ ((row & 7) << 4)));
                    sacc[ni] = __builtin_amdgcn_mfma_f32_16x16x32_bf16(qa[ch], kf, sacc[ni], 0, 0, 0);
                }
            }
            __builtin_amdgcn_s_setprio(0);
            const bool diag = (s0 == q0);
            float sv[4][4];
            float tm[4] = {-1e30f, -1e30f, -1e30f, -1e30f};
#pragma unroll
            for (int ni = 0; ni < 4; ni++)
#pragma unroll
                for (int r = 0; r < 4; r++) {
                    float x = sacc[ni][r];
                    if (diag && (ni * 16 + fr > wid * 16 + kg * 4 + r)) x = -1e30f;
                    sv[ni][r] = x;
                    tm[r] = fmaxf(tm[r], x);
                }
#pragma unroll
            for (int r = 0; r < 4; r++)
#pragma unroll
                for (int off = 1; off < 16; off <<= 1)
                    tm[r] = fmaxf(tm[r], __shfl_xor(tm[r], off));
            int ok = 1;
#pragma unroll
            for (int r = 0; r < 4; r++) ok &= (tm[r] <= mrow[r] + 8.0f);
            if (!__all(ok)) {
#pragma unroll
                for (int r = 0; r < 4; r++) {
                    float mnew = fmaxf(mrow[r], tm[r]);
                    float sc = __expf(mrow[r] - mnew);
                    mrow[r] = mnew;
                    lrow[r] *= sc;
#pragma unroll
                    for (int di = 0; di < 8; di++) oacc[di][r] *= sc;
                }
            }
#pragma unroll
            for (int ni = 0; ni < 4; ni++)
#pragma unroll
                for (int r = 0; r < 4; r++) {
                    float p = __expf(sv[ni][r] - mrow[r]);
                    sv[ni][r] = p;
                    lrow[r] += p;
                }
#pragma unroll
            for (int ni = 0; ni < 4; ni++)
#pragma unroll
                for (int r = 0; r < 4; r++) {
                    int row = kg * 4 + r;
                    int cb = (ni * 16 + fr) * 2;
                    *(short*)((char*)Ps + wid * 2048 + row * 128 +
                              (cb ^ ((row & 7) << 4) ^ ((row & 8) << 2))) = f2b(sv[ni][r]);
                }
            s16x8 pa[2];
#pragma unroll
            for (int sc2 = 0; sc2 < 2; sc2++)
                pa[sc2] = *(const s16x8*)((char*)Ps + wid * 2048 + fr * 128 +
                                          ((sc2 * 64 + kg * 16) ^ ((fr & 7) << 4) ^ ((fr & 8) << 2)));
            __builtin_amdgcn_s_setprio(1);
#pragma unroll
            for (int di = 0; di < 8; di++) {
                int row = di * 16 + fr;
#pragma unroll
                for (int sc2 = 0; sc2 < 2; sc2++) {
                    s16x8 vf = *(const s16x8*)((char*)Vs + row * 128 +
                                               ((sc2 * 64 + kg * 16) ^ ((row & 7) << 4)));
                    oacc[di] = __builtin_amdgcn_mfma_f32_16x16x32_bf16(pa[sc2], vf, oacc[di], 0, 0, 0);
                }
            }
            __builtin_amdgcn_s_setprio(0);
            __syncthreads();
            if (nxt >= 0) WRITEKV();
            __syncthreads();
        }
        // deferred l reduce
#pragma unroll
        for (int r = 0; r < 4; r++)
#pragma unroll
            for (int off = 1; off < 16; off <<= 1)
                lrow[r] += __shfl_xor(lrow[r], off);
        // coalesced O epilogue through the wave-private Ps slot (dead now)
        {
            char* Pw = (char*)Ps + wid * 2048;
#pragma unroll
            for (int r = 0; r < 4; r++) {
                float rl = 1.f / lrow[r];
#pragma unroll
                for (int di = 0; di < 8; di++)
                    *(short*)(Pw + kg * 288 + di * 32 + fr * 2) = f2b(oacc[di][r] * rl);
                asm volatile("s_waitcnt lgkmcnt(0)" ::: "memory");
                int qg = q0 + wid * 16 + kg * 4 + r;
                s16x8 v8 = *(const s16x8*)(Pw + kg * 288 + fr * 16);
                *(s16x8*)(O + (size_t)(b * L_ + qg) * E_ + h * D_ + fr * 8) = v8;
            }
        }
    }
#undef LOADKV
#undef WRITEKV
}

extern "C" void kernel_launch(void* const* d_in, const int* in_sizes, int n_in,
                              void* d_out, int out_size, void* d_ws, size_t ws_size,
                              hipStream_t stream) {
    const float* x     = (const float*)d_in[0];
    const float* wqkv  = (const float*)d_in[1];
    const float* bqkv  = (const float*)d_in[2];
    const float* wout  = (const float*)d_in[3];
    const float* bout  = (const float*)d_in[4];
    float* out = (float*)d_out;
    char* ws = (char*)d_ws;

    const size_t SZ_XB    = (size_t)4096 * 2048 * 2;
    const size_t SZ_WQKV  = (size_t)6144 * 2048 * 2;
    const size_t SZ_WOUT  = (size_t)2048 * 2048 * 2;
    const size_t SZ_QKV   = (size_t)4096 * 6144 * 2;   // reserved (unused)
    const size_t SZ_HLD   = (size_t)32 * 2048 * 128 * 2;
    short* xb    = (short*)(ws);
    short* wqkvb = (short*)(ws + SZ_XB);
    short* woutb = (short*)(ws + SZ_XB + SZ_WQKV);
    short* qb    = (short*)(ws + SZ_XB + SZ_WQKV + SZ_WOUT + SZ_QKV);
    short* kb    = (short*)(ws + SZ_XB + SZ_WQKV + SZ_WOUT + SZ_QKV + SZ_HLD);
    short* vtb   = (short*)(ws + SZ_XB + SZ_WQKV + SZ_WOUT + SZ_QKV + 2 * SZ_HLD);
    float2* trig = (float2*)(ws + SZ_XB + SZ_WQKV + SZ_WOUT + SZ_QKV + 3 * SZ_HLD);
    short* ob    = xb;  // alias: xb dead after gemm_qkv
    const size_t NEEDED = SZ_XB + SZ_WQKV + SZ_WOUT + SZ_QKV + 3 * SZ_HLD + (size_t)L_ * 64 * 8;
    if (ws_size < NEEDED) return;

    prep_kernel<<<25088, 256, 0, stream>>>(x, wqkv, wout, xb, wqkvb, woutb, trig);

    gemm_qkv<<<dim3(32, 48), 256, 0, stream>>>(xb, wqkvb, bqkv, trig, qb, kb, vtb,
                                               4096, 6144, 2048);
    attn_kernel<<<512, 256, 0, stream>>>(qb, kb, vtb, ob);
    gemm_bt<<<dim3(32, 16), 256, 0, stream>>>(ob, woutb, bout, out, 4096, 2048, 2048);
}

// Round 22
// 253.052 us; speedup vs baseline: 1.4237x; 1.4237x over previous
//
#include <hip/hip_runtime.h>
#include <hip/hip_bf16.h>

typedef __attribute__((ext_vector_type(8))) short s16x8;
typedef __attribute__((ext_vector_type(4))) short s16x4;
typedef __attribute__((ext_vector_type(4))) float f32x4;

#define B_ 2
#define L_ 2048
#define E_ 2048
#define H_ 16
#define D_ 128

__device__ __forceinline__ float b2f(short s) {
    unsigned u = ((unsigned)(unsigned short)s) << 16;
    return __builtin_bit_cast(float, u);
}
__device__ __forceinline__ short f2b(float f) {
    unsigned u = __builtin_bit_cast(unsigned, f);
    unsigned r = u + 0x7FFFu + ((u >> 16) & 1u);
    return (short)(r >> 16);
}

__device__ __forceinline__ void lds16(const short* g, short* l) {
    __builtin_amdgcn_global_load_lds(
        (const __attribute__((address_space(1))) void*)g,
        (__attribute__((address_space(3))) void*)l, 16, 0, 0);
}

// ---------------- prep: fp32->bf16 convert (3 tensors) + RoPE trig table ----------------
__global__ __launch_bounds__(256) void prep_kernel(const float* __restrict__ x,
                                                   const float* __restrict__ wq,
                                                   const float* __restrict__ wo,
                                                   short* __restrict__ xb,
                                                   short* __restrict__ wqb,
                                                   short* __restrict__ wob,
                                                   float2* __restrict__ tab) {
    const int blk = blockIdx.x;
    if (blk < 24576) {
        int i = blk * 256 + threadIdx.x;       // over 6291456 float4s
        const float* in; short* out; int idx;
        if (i < 2097152)        { in = x;  out = xb;  idx = i; }
        else if (i < 5242880)   { in = wq; out = wqb; idx = i - 2097152; }
        else                    { in = wo; out = wob; idx = i - 5242880; }
        float4 v = ((const float4*)in)[idx];
        s16x4 o;
        o.x = f2b(v.x); o.y = f2b(v.y); o.z = f2b(v.z); o.w = f2b(v.w);
        ((s16x4*)out)[idx] = o;
    } else {
        int i = (blk - 24576) * 256 + threadIdx.x;   // L * 64 = 131072
        int l = i >> 6, f = i & 63;
        float inv = expf(-(float)(2 * f) * (9.210340371976184f / 128.f));
        float ang = (float)l * inv;
        tab[i] = make_float2(cosf(ang), sinf(ang));
    }
}

// ======== shared BK=64 GEMM core (128x128 tile, 4 waves, T2 swizzle) ========
// LDS rows are 128 B (8 x 16B chunks); read chunk = (ks*4+kg) ^ (fr&7) -> each
// 16-lane group covers all 8 slots 2x = 2-way = free. Staging source column
// pre-swizzled with the same involution (rule #21), LDS dest linear.
// BK=64 halves the per-K-loop barrier+vmcnt-drain count vs BK=32.
#define GEMM_CORE_BK64(A_, B_ptr, K_)                                          \
    const int srow8 = lane >> 3;                                               \
    const int scol = ((lane & 7) ^ srow8) * 8;                                 \
    const short* ga = A_ + (size_t)(m0 + wid * 32 + srow8) * K_ + scol;        \
    const short* gb = B_ptr + (size_t)(n0 + wid * 32 + srow8) * K_ + scol;     \
    short* lA = As + wid * 2048;                                               \
    short* lB = Bs + wid * 2048;                                               \
    for (int kt = 0; kt < K_; kt += 64) {                                      \
        _Pragma("unroll")                                                      \
        for (int c = 0; c < 4; c++) {                                          \
            lds16(ga + kt + (size_t)(c * 8) * K_, lA + c * 512);               \
            lds16(gb + kt + (size_t)(c * 8) * K_, lB + c * 512);               \
        }                                                                      \
        __syncthreads();                                                       \
        _Pragma("unroll")                                                      \
        for (int ks = 0; ks < 2; ks++) {                                       \
            s16x8 af[4], bf[4];                                                \
            _Pragma("unroll")                                                  \
            for (int i = 0; i < 4; i++) {                                      \
                af[i] = *(const s16x8*)(As + (wm + i * 16 + fr) * 64 +         \
                                        (((ks * 4 + kg) ^ (fr & 7)) * 8));     \
                bf[i] = *(const s16x8*)(Bs + (wn + i * 16 + fr) * 64 +         \
                                        (((ks * 4 + kg) ^ (fr & 7)) * 8));     \
            }                                                                  \
            _Pragma("unroll")                                                  \
            for (int mi = 0; mi < 4; mi++)                                     \
                _Pragma("unroll")                                              \
                for (int ni = 0; ni < 4; ni++)                                 \
                    acc[mi][ni] = __builtin_amdgcn_mfma_f32_16x16x32_bf16(     \
                        af[mi], bf[ni], acc[mi][ni], 0, 0, 0);                 \
        }                                                                      \
        __syncthreads();                                                       \
    }

// ---------------- GEMM1 fused: qkv projection + bias + RoPE + rearrange ----------------
// q/k epilogue: direct stores (scalar stores are hidden; LDS round-trip
// variant measured -4.5 us). v: LDS transpose, vec8 writes.
__global__ __launch_bounds__(256, 2)
void gemm_qkv(const short* __restrict__ A, const short* __restrict__ Bm,
              const float* __restrict__ bias, const float2* __restrict__ trig,
              short* __restrict__ q, short* __restrict__ k, short* __restrict__ vt,
              int M, int N, int K) {
    __shared__ __align__(16) char smem[128 * 136 * 2];   // 34816 B
    short* As = (short*)smem;                 // 128*64 shorts (16 KB)
    short* Bs = (short*)(smem + 16384);       // 128*64 shorts (16 KB)
    short* Vt = (short*)smem;                 // [128 d][136 l] after K-loop
    const int t = threadIdx.x;
    const int wid = t >> 6, lane = t & 63;
    const int fr = lane & 15, kg = lane >> 4;
    const int m0 = blockIdx.x * 128, n0 = blockIdx.y * 128;
    const int wm = (wid >> 1) * 64, wn = (wid & 1) * 64;
    f32x4 acc[4][4] = {};

    GEMM_CORE_BK64(A, Bm, K)

    const int part = blockIdx.y >> 4;         // 0=q 1=k 2=v
    const int h = blockIdx.y & 15;
    const int b = m0 >> 11;
    const int l0b = m0 & 2047;
    const size_t bh = (size_t)(b * 16 + h);

    if (part < 2) {
        short* dst = part ? k : q;
        const float qs = part ? 1.0f : 0.08838834764831845f;
#pragma unroll
        for (int mi = 0; mi < 4; mi++) {
#pragma unroll
            for (int ni = 0; ni < 4; ni++) {
                const int dcol = wn + ni * 16 + fr;
                const float bv = bias[n0 + dcol];
#pragma unroll
                for (int r = 0; r < 4; r++) {
                    const int l = l0b + wm + mi * 16 + kg * 4 + r;
                    float vv = (acc[mi][ni][r] + bv) * qs;
                    float other = __shfl_xor(vv, 1);
                    float x0 = (fr & 1) ? other : vv;
                    float x1 = (fr & 1) ? vv : other;
                    float2 cs = trig[l * 64 + (dcol >> 1)];
                    float outv = (fr & 1) ? (x1 * cs.x + x0 * cs.y)
                                          : (x0 * cs.x - x1 * cs.y);
                    dst[(bh * L_ + l) * D_ + dcol] = f2b(outv);
                }
            }
        }
    } else {
        // v: transpose through LDS, write (B,H,D,L) coalesced
#pragma unroll
        for (int mi = 0; mi < 4; mi++) {
#pragma unroll
            for (int ni = 0; ni < 4; ni++) {
                const int dcol = wn + ni * 16 + fr;
                const float bv = bias[n0 + dcol];
#pragma unroll
                for (int r = 0; r < 4; r++) {
                    const int lloc = wm + mi * 16 + kg * 4 + r;
                    Vt[dcol * 136 + lloc] = f2b(acc[mi][ni][r] + bv);
                }
            }
        }
        __syncthreads();
        const int d = t >> 1, lh2 = (t & 1) * 64;
#pragma unroll
        for (int ps = 0; ps < 8; ps++) {
            const int ll = lh2 + ps * 8;
            s16x8 v8 = *(const s16x8*)(Vt + d * 136 + ll);
            *(s16x8*)(vt + (bh * D_ + d) * L_ + l0b + ll) = v8;
        }
    }
}

// ---------------- GEMM2 C[M,N] = A[M,K] * B[N,K]^T + bias (BK=64) ----------------
__global__ __launch_bounds__(256, 2)
void gemm_bt(const short* __restrict__ A, const short* __restrict__ Bm,
             const float* __restrict__ bias, float* __restrict__ C,
             int M, int N, int K) {
    __shared__ __align__(16) short As[128 * 64];
    __shared__ __align__(16) short Bs[128 * 64];
    const int t = threadIdx.x;
    const int wid = t >> 6, lane = t & 63;
    const int fr = lane & 15, kg = lane >> 4;
    const int m0 = blockIdx.x * 128, n0 = blockIdx.y * 128;
    const int wm = (wid >> 1) * 64, wn = (wid & 1) * 64;
    f32x4 acc[4][4] = {};

    GEMM_CORE_BK64(A, Bm, K)

#pragma unroll
    for (int mi = 0; mi < 4; mi++) {
#pragma unroll
        for (int ni = 0; ni < 4; ni++) {
            int gn = n0 + wn + ni * 16 + fr;
            float bv = bias[gn];
#pragma unroll
            for (int r = 0; r < 4; r++) {
                int gm = m0 + wm + mi * 16 + kg * 4 + r;
                C[(size_t)gm * N + gn] = acc[mi][ni][r] + bv;
            }
        }
    }
}

// ---------------- causal flash attention: uniform-work q-tile pairs + T14 reg-staging ----------------
// (r10 structure; O epilogue coalesced through the per-wave Ps slot)
__global__ __launch_bounds__(256, 2)
void attn_kernel(const short* __restrict__ Q, const short* __restrict__ Kb,
                 const short* __restrict__ Vt, short* __restrict__ O) {
    __shared__ __align__(16) short Ks[64 * 128];   // [s][d] swizzled
    __shared__ __align__(16) short Vs[128 * 64];   // [d][s] swizzled
    __shared__ __align__(16) short Ps[4 * 16 * 64];
    const int t = threadIdx.x;
    const int wid = t >> 6, lane = t & 63;
    const int fr = lane & 15, kg = lane >> 4;
    const int bid = blockIdx.x;
    const int qp = bid & 15, bh = bid >> 4;   // 512 blocks: 16 pairs x 32 bh
    const int b = bh >> 4, h = bh & 15;
    const size_t base = (size_t)bh * (L_ * D_);

    const int rr = t >> 4, c16 = t & 15;      // K staging map
    const int dr = t >> 3, lg2 = t & 7;       // V staging map

    s16x8 kreg[4], vreg[4];
#define LOADKV(s0v) { _Pragma("unroll")                                        \
    for (int it = 0; it < 4; it++) {                                           \
        kreg[it] = *(const s16x8*)(Kb + base + (size_t)((s0v) + it * 16 + rr) * D_ + c16 * 8); \
        vreg[it] = *(const s16x8*)(Vt + base + (size_t)(it * 32 + dr) * L_ + (s0v) + lg2 * 8); \
    } }
#define WRITEKV() { _Pragma("unroll")                                          \
    for (int it = 0; it < 4; it++) {                                           \
        int row = it * 16 + rr;                                                \
        *(s16x8*)((char*)Ks + row * 256 + ((c16 * 16) ^ ((row & 7) << 4))) = kreg[it]; \
        int d = it * 32 + dr;                                                  \
        *(s16x8*)((char*)Vs + d * 128 + ((lg2 * 16) ^ ((d & 7) << 4))) = vreg[it]; \
    } }

    LOADKV(0);
    WRITEKV();
    __syncthreads();

    for (int ph = 0; ph < 2; ph++) {
        const int qt = ph ? (31 - qp) : qp;
        const int q0 = qt << 6;
        s16x8 qa[4];
        {
            const short* qptr = Q + base + (size_t)(q0 + wid * 16 + fr) * D_ + kg * 8;
#pragma unroll
            for (int ch = 0; ch < 4; ch++) qa[ch] = *(const s16x8*)(qptr + ch * 32);
        }
        f32x4 oacc[8] = {};
        float mrow[4], lrow[4];
#pragma unroll
        for (int r = 0; r < 4; r++) { mrow[r] = -1e30f; lrow[r] = 0.f; }

        const int ntile = qt + 1;
        for (int ti = 0; ti < ntile; ti++) {
            const int s0 = ti << 6;
            const int nxt = (ti + 1 < ntile) ? (s0 + 64) : (ph == 0 ? 0 : -1);
            if (nxt >= 0) LOADKV(nxt);
            f32x4 sacc[4] = {};
            __builtin_amdgcn_s_setprio(1);
#pragma unroll
            for (int ch = 0; ch < 4; ch++) {
#pragma unroll
                for (int ni = 0; ni < 4; ni++) {
                    int row = ni * 16 + fr;
                    s16x8 kf = *(const s16x8*)((char*)Ks + row * 256 +
                                               ((ch * 64 + kg * 16) ^ ((row & 7) << 4)));
                    sacc[ni] = __builtin_amdgcn_mfma_f32_16x16x32_bf16(qa[ch], kf, sacc[ni], 0, 0, 0);
                }
            }
            __builtin_amdgcn_s_setprio(0);
            const bool diag = (s0 == q0);
            float sv[4][4];
            float tm[4] = {-1e30f, -1e30f, -1e30f, -1e30f};
#pragma unroll
            for (int ni = 0; ni < 4; ni++)
#pragma unroll
                for (int r = 0; r < 4; r++) {
                    float x = sacc[ni][r];
                    if (diag && (ni * 16 + fr > wid * 16 + kg * 4 + r)) x = -1e30f;
                    sv[ni][r] = x;
                    tm[r] = fmaxf(tm[r], x);
                }
#pragma unroll
            for (int r = 0; r < 4; r++)
#pragma unroll
                for (int off = 1; off < 16; off <<= 1)
                    tm[r] = fmaxf(tm[r], __shfl_xor(tm[r], off));
            int ok = 1;
#pragma unroll
            for (int r = 0; r < 4; r++) ok &= (tm[r] <= mrow[r] + 8.0f);
            if (!__all(ok)) {
#pragma unroll
                for (int r = 0; r < 4; r++) {
                    float mnew = fmaxf(mrow[r], tm[r]);
                    float sc = __expf(mrow[r] - mnew);
                    mrow[r] = mnew;
                    lrow[r] *= sc;
#pragma unroll
                    for (int di = 0; di < 8; di++) oacc[di][r] *= sc;
                }
            }
#pragma unroll
            for (int ni = 0; ni < 4; ni++)
#pragma unroll
                for (int r = 0; r < 4; r++) {
                    float p = __expf(sv[ni][r] - mrow[r]);
                    sv[ni][r] = p;
                    lrow[r] += p;
                }
#pragma unroll
            for (int ni = 0; ni < 4; ni++)
#pragma unroll
                for (int r = 0; r < 4; r++) {
                    int row = kg * 4 + r;
                    int cb = (ni * 16 + fr) * 2;
                    *(short*)((char*)Ps + wid * 2048 + row * 128 +
                              (cb ^ ((row & 7) << 4) ^ ((row & 8) << 2))) = f2b(sv[ni][r]);
                }
            s16x8 pa[2];
#pragma unroll
            for (int sc2 = 0; sc2 < 2; sc2++)
                pa[sc2] = *(const s16x8*)((char*)Ps + wid * 2048 + fr * 128 +
                                          ((sc2 * 64 + kg * 16) ^ ((fr & 7) << 4) ^ ((fr & 8) << 2)));
            __builtin_amdgcn_s_setprio(1);
#pragma unroll
            for (int di = 0; di < 8; di++) {
                int row = di * 16 + fr;
#pragma unroll
                for (int sc2 = 0; sc2 < 2; sc2++) {
                    s16x8 vf = *(const s16x8*)((char*)Vs + row * 128 +
                                               ((sc2 * 64 + kg * 16) ^ ((row & 7) << 4)));
                    oacc[di] = __builtin_amdgcn_mfma_f32_16x16x32_bf16(pa[sc2], vf, oacc[di], 0, 0, 0);
                }
            }
            __builtin_amdgcn_s_setprio(0);
            __syncthreads();
            if (nxt >= 0) WRITEKV();
            __syncthreads();
        }
        // deferred l reduce
#pragma unroll
        for (int r = 0; r < 4; r++)
#pragma unroll
            for (int off = 1; off < 16; off <<= 1)
                lrow[r] += __shfl_xor(lrow[r], off);
        // coalesced O epilogue through the wave-private Ps slot (dead now)
        {
            char* Pw = (char*)Ps + wid * 2048;
#pragma unroll
            for (int r = 0; r < 4; r++) {
                float rl = 1.f / lrow[r];
#pragma unroll
                for (int di = 0; di < 8; di++)
                    *(short*)(Pw + kg * 288 + di * 32 + fr * 2) = f2b(oacc[di][r] * rl);
                asm volatile("s_waitcnt lgkmcnt(0)" ::: "memory");
                int qg = q0 + wid * 16 + kg * 4 + r;
                s16x8 v8 = *(const s16x8*)(Pw + kg * 288 + fr * 16);
                *(s16x8*)(O + (size_t)(b * L_ + qg) * E_ + h * D_ + fr * 8) = v8;
            }
        }
    }
#undef LOADKV
#undef WRITEKV
}

extern "C" void kernel_launch(void* const* d_in, const int* in_sizes, int n_in,
                              void* d_out, int out_size, void* d_ws, size_t ws_size,
                              hipStream_t stream) {
    const float* x     = (const float*)d_in[0];
    const float* wqkv  = (const float*)d_in[1];
    const float* bqkv  = (const float*)d_in[2];
    const float* wout  = (const float*)d_in[3];
    const float* bout  = (const float*)d_in[4];
    float* out = (float*)d_out;
    char* ws = (char*)d_ws;

    const size_t SZ_XB    = (size_t)4096 * 2048 * 2;
    const size_t SZ_WQKV  = (size_t)6144 * 2048 * 2;
    const size_t SZ_WOUT  = (size_t)2048 * 2048 * 2;
    const size_t SZ_QKV   = (size_t)4096 * 6144 * 2;   // reserved (unused)
    const size_t SZ_HLD   = (size_t)32 * 2048 * 128 * 2;
    short* xb    = (short*)(ws);
    short* wqkvb = (short*)(ws + SZ_XB);
    short* woutb = (short*)(ws + SZ_XB + SZ_WQKV);
    short* qb    = (short*)(ws + SZ_XB + SZ_WQKV + SZ_WOUT + SZ_QKV);
    short* kb    = (short*)(ws + SZ_XB + SZ_WQKV + SZ_WOUT + SZ_QKV + SZ_HLD);
    short* vtb   = (short*)(ws + SZ_XB + SZ_WQKV + SZ_WOUT + SZ_QKV + 2 * SZ_HLD);
    float2* trig = (float2*)(ws + SZ_XB + SZ_WQKV + SZ_WOUT + SZ_QKV + 3 * SZ_HLD);
    short* ob    = xb;  // alias: xb dead after gemm_qkv
    const size_t NEEDED = SZ_XB + SZ_WQKV + SZ_WOUT + SZ_QKV + 3 * SZ_HLD + (size_t)L_ * 64 * 8;
    if (ws_size < NEEDED) return;

    prep_kernel<<<25088, 256, 0, stream>>>(x, wqkv, wout, xb, wqkvb, woutb, trig);

    gemm_qkv<<<dim3(32, 48), 256, 0, stream>>>(xb, wqkvb, bqkv, trig, qb, kb, vtb,
                                               4096, 6144, 2048);
    attn_kernel<<<512, 256, 0, stream>>>(qb, kb, vtb, ob);
    gemm_bt<<<dim3(32, 16), 256, 0, stream>>>(ob, woutb, bout, out, 4096, 2048, 2048);
}